// Round 13
// baseline (287.599 us; speedup 1.0000x reference)
//
#include <hip/hip_runtime.h>
#include <hip/hip_bf16.h>
#include <hip/hip_fp16.h>

#define NN 100000      // nodes
#define NE 1600000     // edges
#define NP 100000      // pos/neg label edges
// EMB=64, HID=128, OUT=64

// ---------------- fp16 helpers ----------------
typedef _Float16 h2v __attribute__((ext_vector_type(2)));

__device__ __forceinline__ float fdot2u(uint a, uint b, float c) {
    union { uint u; h2v h; } ua, ub;
    ua.u = a; ub.u = b;
    return __builtin_amdgcn_fdot2(ua.h, ub.h, c, false);
}

__device__ __forceinline__ uint packh2(float lo, float hi) {
    __half2 h = __floats2half2_rn(lo, hi);
    return *(uint*)&h;
}

__device__ __forceinline__ void h8_to_f(const uint4 u, float* f) {
    const __half2* hp = (const __half2*)&u;
    float2 t0 = __half22float2(hp[0]), t1 = __half22float2(hp[1]);
    float2 t2 = __half22float2(hp[2]), t3 = __half22float2(hp[3]);
    f[0] = t0.x; f[1] = t0.y; f[2] = t1.x; f[3] = t1.y;
    f[4] = t2.x; f[5] = t2.y; f[6] = t3.x; f[7] = t3.y;
}

__device__ __forceinline__ void add8(const uint4 u, float* acc) {
    float f[8]; h8_to_f(u, f);
#pragma unroll
    for (int i = 0; i < 8; ++i) acc[i] += f[i];
}

// ---------------- CSR build: bucket histogram -> scan -> 2-pass counting sort --------
#define RNG 400
#define NBK 250       // NN / RNG
#define K_A 8000      // edges per pass-A block; 200 blocks
#define CAPB 12288    // pass-B LDS staging (mean region 6400)

__global__ __launch_bounds__(256) void k_hist(const int* __restrict__ ei,
                                              int* __restrict__ bcnt) {
    __shared__ int hist[NBK];
    int tid = threadIdx.x;
    int e0 = blockIdx.x * K_A;
    for (int i = tid; i < NBK; i += 256) hist[i] = 0;
    __syncthreads();
    for (int i = tid; i < K_A; i += 256) atomicAdd(&hist[ei[NE + e0 + i] / RNG], 1);
    __syncthreads();
    for (int i = tid; i < NBK; i += 256) if (hist[i]) atomicAdd(&bcnt[i], hist[i]);
}

__global__ __launch_bounds__(256) void k_bscan(const int* __restrict__ bcnt,
                                               int* __restrict__ bbase,
                                               int* __restrict__ gcnt) {
    __shared__ int c[NBK];
    int tid = threadIdx.x;
    if (tid < NBK) c[tid] = bcnt[tid];
    __syncthreads();
    if (tid < 64) {
        int run = 0;
        for (int g = 0; g < NBK; g += 64) {
            int idx = g + tid;
            int v = (idx < NBK) ? c[idx] : 0;
            int inc = v;
#pragma unroll
            for (int off = 1; off < 64; off <<= 1) {
                int t2 = __shfl_up(inc, off);
                if (tid >= off) inc += t2;
            }
            if (idx < NBK) { int ex = run + inc - v; bbase[idx] = ex; gcnt[idx] = ex; }
            run += __shfl(inc, 63);
        }
        if (tid == 0) bbase[NBK] = run;
    }
}

// Pass A: chunk -> bucket-sorted in LDS -> coalesced segment append per bucket.
// Record (4B): src | (dst_local << 17)
__global__ __launch_bounds__(256) void k_binA(const int* __restrict__ ei,
                                              int* __restrict__ gcnt,
                                              int* __restrict__ edges) {
    __shared__ int buf[K_A];                        // 32 KB
    __shared__ int hist[NBK], lofs[NBK + 1], lcnt[NBK], gbase[NBK];
    int tid = threadIdx.x;
    int e0 = blockIdx.x * K_A;
    for (int i = tid; i < NBK; i += 256) { hist[i] = 0; lcnt[i] = 0; }
    __syncthreads();
    for (int i = tid; i < K_A; i += 256) atomicAdd(&hist[ei[NE + e0 + i] / RNG], 1);
    __syncthreads();
    if (tid < 64) {
        int run = 0;
        for (int g = 0; g < NBK; g += 64) {
            int idx = g + tid;
            int v = (idx < NBK) ? hist[idx] : 0;
            int inc = v;
#pragma unroll
            for (int off = 1; off < 64; off <<= 1) {
                int t2 = __shfl_up(inc, off);
                if (tid >= off) inc += t2;
            }
            if (idx < NBK) lofs[idx] = run + inc - v;
            run += __shfl(inc, 63);
        }
        if (tid == 0) lofs[NBK] = run;              // == K_A
    }
    for (int i = tid; i < NBK; i += 256) gbase[i] = atomicAdd(&gcnt[i], hist[i]);
    __syncthreads();
    for (int i = tid; i < K_A; i += 256) {
        int s = ei[e0 + i], d = ei[NE + e0 + i];
        int b = d / RNG;
        int dl = d - b * RNG;
        int p = lofs[b] + atomicAdd(&lcnt[b], 1);
        buf[p] = s | (dl << 17);
    }
    __syncthreads();
    for (int j = tid; j < K_A; j += 256) {
        int loB = 0, hiB = NBK;
        while (hiB - loB > 1) {
            int mid = (loB + hiB) >> 1;
            if (lofs[mid] <= j) loB = mid; else hiB = mid;
        }
        edges[gbase[loB] + (j - lofs[loB])] = buf[j];
    }
}

// Pass B: per bucket -- per-dst histogram -> dinv + rowptr, then in-place CSR reorder.
__global__ __launch_bounds__(256) void k_binB(const int* __restrict__ bbase,
                                              int* __restrict__ edges,
                                              int* __restrict__ rowptr,
                                              float* __restrict__ dinv) {
    __shared__ int buf[CAPB];                       // 48 KB
    __shared__ int hist[RNG], lrp[RNG], lcnt[RNG];
    int tid = threadIdx.x;
    int b = blockIdx.x;
    int lo = b * RNG;
    int base = bbase[b], n = bbase[b + 1] - base;
    for (int i = tid; i < RNG; i += 256) { hist[i] = 0; lcnt[i] = 0; }
    __syncthreads();
    for (int i = tid; i < n; i += 256)
        atomicAdd(&hist[((unsigned)edges[base + i]) >> 17], 1);
    __syncthreads();
    if (tid < 64) {
        int run = 0;
        for (int g = 0; g < RNG; g += 64) {
            int idx = g + tid;
            int v = (idx < RNG) ? hist[idx] : 0;
            int inc = v;
#pragma unroll
            for (int off = 1; off < 64; off <<= 1) {
                int t2 = __shfl_up(inc, off);
                if (tid >= off) inc += t2;
            }
            if (idx < RNG) lrp[idx] = run + inc - v;
            run += __shfl(inc, 63);
        }
    }
    __syncthreads();
    for (int i = tid; i < RNG; i += 256) {
        dinv[lo + i] = rsqrtf((float)hist[i] + 1.0f);
        rowptr[lo + i] = base + lrp[i];
    }
    if (b == NBK - 1 && tid == 0) rowptr[NN] = base + n;
    int ovS0 = -1, ovS1 = -1, ovR0 = 0, ovR1 = 0;
    for (int i = tid; i < n; i += 256) {
        int rec = edges[base + i];
        int dl = ((unsigned)rec) >> 17;
        int src = rec & 0x1FFFF;
        int slot = lrp[dl] + atomicAdd(&lcnt[dl], 1);
        if (slot < CAPB) buf[slot] = src;
        else if (ovS0 < 0) { ovS0 = slot; ovR0 = src; }
        else { ovS1 = slot; ovR1 = src; }
    }
    __syncthreads();
    int lim = n < CAPB ? n : CAPB;
    for (int i = tid; i < lim; i += 256) edges[base + i] = buf[i];
    if (ovS0 >= 0) edges[base + ovS0] = ovR0;
    if (ovS1 >= 0) edges[base + ovS1] = ovR1;
}

// ---------------- emb -> fp16 table, pre-scaled by dinv ----------------
__global__ void k_cvt(const float4* __restrict__ in4, const float* __restrict__ dinv,
                      uint4* __restrict__ out) {
    int t = blockIdx.x * blockDim.x + threadIdx.x;   // NN*8 threads, 8 floats each
    if (t >= NN * 8) return;
    float dv = dinv[t >> 3];
    float4 a = in4[t * 2], b = in4[t * 2 + 1];
    union { __half2 h[4]; uint4 u; } pk;
    pk.h[0] = __floats2half2_rn(a.x * dv, a.y * dv);
    pk.h[1] = __floats2half2_rn(a.z * dv, a.w * dv);
    pk.h[2] = __floats2half2_rn(b.x * dv, b.y * dv);
    pk.h[3] = __floats2half2_rn(b.z * dv, b.w * dv);
    out[t] = pk.u;
}

// ---------------- fused layer 1: gather(emb16) -> h' = relu(agg@W1+b1)*dinv ----------
// 512 threads, 64 rows/block. Gather: 8 lanes/row (16B each). LDS 24.5 KB.
__global__ __launch_bounds__(512) void k_l1(const uint4* __restrict__ x16,
                                            const float* __restrict__ dinv,
                                            const int* __restrict__ rowptr,
                                            const int* __restrict__ edges,
                                            const float4* __restrict__ W1_4, // [64][32] f4
                                            const float* __restrict__ b1,
                                            uint2* __restrict__ h16) {
    __shared__ uint4 w16h[32 * 32];    // 16 KB: [kpair][jg] half2 pairs
    __shared__ uint rows16[64 * 32];   // 8 KB: [row][kpair]
    __shared__ float sdinv[64];
    int t = threadIdx.x;
    int base = blockIdx.x * 64;
#pragma unroll
    for (int i = 0; i < 2; ++i) {      // 1024 entries
        int idx = t + i * 512;
        int kp = idx >> 5, jg = idx & 31;
        float4 we = W1_4[(2 * kp) * 32 + jg];
        float4 wo = W1_4[(2 * kp + 1) * 32 + jg];
        w16h[idx] = make_uint4(packh2(we.x, wo.x), packh2(we.y, wo.y),
                               packh2(we.z, wo.z), packh2(we.w, wo.w));
    }
    if (t < 64) sdinv[t] = (base + t < NN) ? dinv[base + t] : 0.0f;
    // ---- gather phase ----
    int rl = t >> 3, q = t & 7;
    int r = base + rl;
    if (r < NN) {
        float acc[8];
        h8_to_f(x16[(size_t)r * 8 + q], acc);        // self term x'[r]
        int j = rowptr[r], j1 = rowptr[r + 1];
        for (; j + 8 <= j1; j += 8) {
            int e[8]; uint4 v[8];
#pragma unroll
            for (int i = 0; i < 8; ++i) e[i] = edges[j + i];
#pragma unroll
            for (int i = 0; i < 8; ++i) v[i] = x16[(size_t)e[i] * 8 + q];
#pragma unroll
            for (int i = 0; i < 8; ++i) add8(v[i], acc);
        }
        if (j + 4 <= j1) {
            int e[4]; uint4 v[4];
#pragma unroll
            for (int i = 0; i < 4; ++i) e[i] = edges[j + i];
#pragma unroll
            for (int i = 0; i < 4; ++i) v[i] = x16[(size_t)e[i] * 8 + q];
#pragma unroll
            for (int i = 0; i < 4; ++i) add8(v[i], acc);
            j += 4;
        }
        for (; j < j1; ++j) add8(x16[(size_t)edges[j] * 8 + q], acc);
        float dr = dinv[r];
#pragma unroll
        for (int i = 0; i < 8; ++i) acc[i] *= dr;
#pragma unroll
        for (int i = 0; i < 4; ++i)
            rows16[rl * 32 + 4 * q + i] = packh2(acc[2 * i], acc[2 * i + 1]);
    }
    __syncthreads();
    // ---- matmul phase: 16 row-groups x 4 rows, 32 col-groups ----
    int rg = t >> 5, jg = t & 31;
    int r0 = rg * 4;
    float4 bias = ((const float4*)b1)[jg];
    float acc[4][4];
#pragma unroll
    for (int r2 = 0; r2 < 4; ++r2) {
        acc[r2][0] = bias.x; acc[r2][1] = bias.y; acc[r2][2] = bias.z; acc[r2][3] = bias.w;
    }
#pragma unroll 4
    for (int kp = 0; kp < 32; ++kp) {
        uint f0 = rows16[(r0 + 0) * 32 + kp];
        uint f1 = rows16[(r0 + 1) * 32 + kp];
        uint f2 = rows16[(r0 + 2) * 32 + kp];
        uint f3 = rows16[(r0 + 3) * 32 + kp];
        uint4 wv = w16h[kp * 32 + jg];
        acc[0][0] = fdot2u(f0, wv.x, acc[0][0]); acc[0][1] = fdot2u(f0, wv.y, acc[0][1]);
        acc[0][2] = fdot2u(f0, wv.z, acc[0][2]); acc[0][3] = fdot2u(f0, wv.w, acc[0][3]);
        acc[1][0] = fdot2u(f1, wv.x, acc[1][0]); acc[1][1] = fdot2u(f1, wv.y, acc[1][1]);
        acc[1][2] = fdot2u(f1, wv.z, acc[1][2]); acc[1][3] = fdot2u(f1, wv.w, acc[1][3]);
        acc[2][0] = fdot2u(f2, wv.x, acc[2][0]); acc[2][1] = fdot2u(f2, wv.y, acc[2][1]);
        acc[2][2] = fdot2u(f2, wv.z, acc[2][2]); acc[2][3] = fdot2u(f2, wv.w, acc[2][3]);
        acc[3][0] = fdot2u(f3, wv.x, acc[3][0]); acc[3][1] = fdot2u(f3, wv.y, acc[3][1]);
        acc[3][2] = fdot2u(f3, wv.z, acc[3][2]); acc[3][3] = fdot2u(f3, wv.w, acc[3][3]);
    }
#pragma unroll
    for (int r2 = 0; r2 < 4; ++r2) {
        int row = base + r0 + r2;
        if (row < NN) {
            float dv = sdinv[r0 + r2];
            union { __half2 h[2]; uint2 u; } pk;
            pk.h[0] = __floats2half2_rn(fmaxf(acc[r2][0], 0.0f) * dv,
                                        fmaxf(acc[r2][1], 0.0f) * dv);
            pk.h[1] = __floats2half2_rn(fmaxf(acc[r2][2], 0.0f) * dv,
                                        fmaxf(acc[r2][3], 0.0f) * dv);
            h16[(size_t)row * 32 + jg] = pk.u;
        }
    }
}

// ---------------- fused layer 2: gather(h16) -> mu/logstd + z16 ----------
// 512 threads, 32 rows/block (NN%32==0, no tail). Gather: 16 lanes/row x 16B,
// 8-edge unroll (aggH's exact MLP shape). LDS 40 KB -> 4 blocks/CU.
__global__ __launch_bounds__(512) void k_l2(const uint4* __restrict__ x16,
                                            const float* __restrict__ dinv,
                                            const int* __restrict__ rowptr,
                                            const int* __restrict__ edges,
                                            const float4* __restrict__ Wmu4, // [128][16] f4
                                            const float* __restrict__ bmu,
                                            const float4* __restrict__ Wls4, // [128][16] f4
                                            const float* __restrict__ bls,
                                            float* __restrict__ out,
                                            uint2* __restrict__ z16) {
    __shared__ uint4 w16h[64 * 32];    // 32 KB: full [Wmu|Wls] as [kpair][jg]
    __shared__ uint rows16[32 * 64];   // 8 KB: [row][kpair]
    int t = threadIdx.x;
    int base = blockIdx.x * 32;
#pragma unroll
    for (int i = 0; i < 4; ++i) {      // 2048 entries
        int idx = t + i * 512;
        int kp = idx >> 5, jg = idx & 31;
        int jj = (jg < 16) ? jg : (jg - 16);
        const float4* W = (jg < 16) ? Wmu4 : Wls4;
        float4 we = W[(2 * kp) * 16 + jj];
        float4 wo = W[(2 * kp + 1) * 16 + jj];
        w16h[idx] = make_uint4(packh2(we.x, wo.x), packh2(we.y, wo.y),
                               packh2(we.z, wo.z), packh2(we.w, wo.w));
    }
    // ---- gather phase: 16 lanes/row, 1 uint4 per lane per edge ----
    int rl = t >> 4, q = t & 15;
    int r = base + rl;
    {
        float acc[8];
        h8_to_f(x16[(size_t)r * 16 + q], acc);       // self term h'[r]
        int j = rowptr[r], j1 = rowptr[r + 1];
        for (; j + 8 <= j1; j += 8) {
            int e[8]; uint4 v[8];
#pragma unroll
            for (int i = 0; i < 8; ++i) e[i] = edges[j + i];
#pragma unroll
            for (int i = 0; i < 8; ++i) v[i] = x16[(size_t)e[i] * 16 + q];
#pragma unroll
            for (int i = 0; i < 8; ++i) add8(v[i], acc);
        }
        if (j + 4 <= j1) {
            int e[4]; uint4 v[4];
#pragma unroll
            for (int i = 0; i < 4; ++i) e[i] = edges[j + i];
#pragma unroll
            for (int i = 0; i < 4; ++i) v[i] = x16[(size_t)e[i] * 16 + q];
#pragma unroll
            for (int i = 0; i < 4; ++i) add8(v[i], acc);
            j += 4;
        }
        for (; j < j1; ++j) add8(x16[(size_t)edges[j] * 16 + q], acc);
        float dr = dinv[r];
#pragma unroll
        for (int i = 0; i < 8; ++i) acc[i] *= dr;
#pragma unroll
        for (int i = 0; i < 4; ++i)
            rows16[rl * 64 + 4 * q + i] = packh2(acc[2 * i], acc[2 * i + 1]);
    }
    __syncthreads();
    // ---- matmul phase: 16 row-pairs x 2 rows, 32 col-groups ----
    int rp = t >> 5, jg = t & 31;
    int r0 = rp * 2;
    float4 bias = (jg < 16) ? ((const float4*)bmu)[jg] : ((const float4*)bls)[jg - 16];
    float acc[2][4];
#pragma unroll
    for (int r2 = 0; r2 < 2; ++r2) {
        acc[r2][0] = bias.x; acc[r2][1] = bias.y; acc[r2][2] = bias.z; acc[r2][3] = bias.w;
    }
#pragma unroll 8
    for (int kp = 0; kp < 64; ++kp) {
        uint f0 = rows16[(r0 + 0) * 64 + kp];
        uint f1 = rows16[(r0 + 1) * 64 + kp];
        uint4 wv = w16h[kp * 32 + jg];
        acc[0][0] = fdot2u(f0, wv.x, acc[0][0]); acc[0][1] = fdot2u(f0, wv.y, acc[0][1]);
        acc[0][2] = fdot2u(f0, wv.z, acc[0][2]); acc[0][3] = fdot2u(f0, wv.w, acc[0][3]);
        acc[1][0] = fdot2u(f1, wv.x, acc[1][0]); acc[1][1] = fdot2u(f1, wv.y, acc[1][1]);
        acc[1][2] = fdot2u(f1, wv.z, acc[1][2]); acc[1][3] = fdot2u(f1, wv.w, acc[1][3]);
    }
    float4* out4 = (float4*)out;
    if (jg < 16) {
#pragma unroll
        for (int r2 = 0; r2 < 2; ++r2) {
            int row = base + r0 + r2;
            out4[(size_t)row * 16 + jg] =
                make_float4(acc[r2][0], acc[r2][1], acc[r2][2], acc[r2][3]);
            union { __half2 h[2]; uint2 u; } pk;
            pk.h[0] = __floats2half2_rn(acc[r2][0], acc[r2][1]);
            pk.h[1] = __floats2half2_rn(acc[r2][2], acc[r2][3]);
            z16[(size_t)row * 16 + jg] = pk.u;
        }
    } else {
#pragma unroll
        for (int r2 = 0; r2 < 2; ++r2) {
            int row = base + r0 + r2;
            float4 o = make_float4(fminf(acc[r2][0], 10.0f), fminf(acc[r2][1], 10.0f),
                                   fminf(acc[r2][2], 10.0f), fminf(acc[r2][3], 10.0f));
            out4[(size_t)NN * 16 + (size_t)row * 16 + (jg - 16)] = o;
        }
    }
}

// ---------------- decoder loss: fp16 z, 4 edges per 16-lane group, fdot2 ----------------
__global__ __launch_bounds__(256) void k_loss(const int* __restrict__ pos,
                                              const int* __restrict__ neg,
                                              const uint2* __restrict__ z16,
                                              float* __restrict__ accum) {
    int t = blockIdx.x * blockDim.x + threadIdx.x;
    int grp = t >> 4, q = t & 15;
    int e0 = grp * 4;                          // 4 consecutive ids in [0, 2*NP)
    bool isNeg = e0 >= NP;                     // uniform within group (NP % 4 == 0)
    const int* idx = isNeg ? neg : pos;
    int eb = isNeg ? e0 - NP : e0;
    int a0 = idx[eb + 0], b0 = idx[NP + eb + 0];
    int a1 = idx[eb + 1], b1 = idx[NP + eb + 1];
    int a2 = idx[eb + 2], b2 = idx[NP + eb + 2];
    int a3 = idx[eb + 3], b3 = idx[NP + eb + 3];
    uint2 ua0 = z16[(size_t)a0 * 16 + q], ub0 = z16[(size_t)b0 * 16 + q];
    uint2 ua1 = z16[(size_t)a1 * 16 + q], ub1 = z16[(size_t)b1 * 16 + q];
    uint2 ua2 = z16[(size_t)a2 * 16 + q], ub2 = z16[(size_t)b2 * 16 + q];
    uint2 ua3 = z16[(size_t)a3 * 16 + q], ub3 = z16[(size_t)b3 * 16 + q];
    float d0 = fdot2u(ua0.y, ub0.y, fdot2u(ua0.x, ub0.x, 0.0f));
    float d1 = fdot2u(ua1.y, ub1.y, fdot2u(ua1.x, ub1.x, 0.0f));
    float d2 = fdot2u(ua2.y, ub2.y, fdot2u(ua2.x, ub2.x, 0.0f));
    float d3 = fdot2u(ua3.y, ub3.y, fdot2u(ua3.x, ub3.x, 0.0f));
#pragma unroll
    for (int off = 1; off < 16; off <<= 1) {
        d0 += __shfl_xor(d0, off);
        d1 += __shfl_xor(d1, off);
        d2 += __shfl_xor(d2, off);
        d3 += __shfl_xor(d3, off);
    }
    __shared__ float bsum[2];
    if (threadIdx.x < 2) bsum[threadIdx.x] = 0.0f;
    __syncthreads();
    if (q == 0) {
        float term;
        if (isNeg) {
            term = logf(1.0f - 1.0f / (1.0f + expf(-d0)) + 1e-15f)
                 + logf(1.0f - 1.0f / (1.0f + expf(-d1)) + 1e-15f)
                 + logf(1.0f - 1.0f / (1.0f + expf(-d2)) + 1e-15f)
                 + logf(1.0f - 1.0f / (1.0f + expf(-d3)) + 1e-15f);
        } else {
            term = logf(1.0f / (1.0f + expf(-d0)) + 1e-15f)
                 + logf(1.0f / (1.0f + expf(-d1)) + 1e-15f)
                 + logf(1.0f / (1.0f + expf(-d2)) + 1e-15f)
                 + logf(1.0f / (1.0f + expf(-d3)) + 1e-15f);
        }
        atomicAdd(&bsum[isNeg ? 1 : 0], term);
    }
    __syncthreads();
    if (threadIdx.x < 2) atomicAdd(&accum[threadIdx.x], bsum[threadIdx.x]);
}

__global__ void k_fin(const float* __restrict__ accum, float* __restrict__ out) {
    out[(size_t)NN * 128] = -(accum[0] + accum[1]) * (1.0f / (float)NP);
}

extern "C" void kernel_launch(void* const* d_in, const int* in_sizes, int n_in,
                              void* d_out, int out_size, void* d_ws, size_t ws_size,
                              hipStream_t stream) {
    const float* emb = (const float*)d_in[0];
    const int*   ei  = (const int*)d_in[1];
    const float* W1  = (const float*)d_in[2];
    const float* b1  = (const float*)d_in[3];
    const float* Wmu = (const float*)d_in[4];
    const float* bmu = (const float*)d_in[5];
    const float* Wls = (const float*)d_in[6];
    const float* bls = (const float*)d_in[7];
    const int*   pos = (const int*)d_in[8];
    const int*   neg = (const int*)d_in[9];
    float* out = (float*)d_out;

    char* ws = (char*)d_ws;
    // small buffers
    float* dinv   = (float*)(ws);                        // 400 KB  (written by k_binB)
    int*   rowptr = (int*)  (ws + (512 << 10));          // 400 KB + 4 (written by k_binB)
    int*   bcnt   = (int*)  (ws + (1024 << 10));         // 1 KB
    int*   bbase  = (int*)  (ws + (1028 << 10));         // 1 KB + 4
    int*   gcnt   = (int*)  (ws + (1032 << 10));         // 1 KB
    float* accum  = (float*)(ws + (1040 << 10));         // 8 B
    // big buffers. Liveness:
    //   edges  [k_binA .. k_l2]                            6.4 MB (4B records)
    //   h16    [k_l1 .. k_l2]                              25.6 MB
    //   emb16  [k_cvt .. k_l1]                             12.8 MB
    //   z16    [k_l2 .. k_loss]   ALIASES emb16 (dead)     12.8 MB
    const size_t OFF_EDGES = (2048 << 10);                       // +6.4 MB
    const size_t OFF_H16   = OFF_EDGES + (size_t)NE * 4;         // +25.6 MB
    const size_t OFF_E16   = OFF_H16 + (size_t)NN * 128 * 2;     // +12.8 MB
    int*   edges  = (int*)(ws + OFF_EDGES);
    uint2* h16    = (uint2*)(ws + OFF_H16);
    uint4* emb16  = (uint4*)(ws + OFF_E16);
    uint2* z16    = (uint2*)(ws + OFF_E16);              // emb16 dead by k_l2

    hipMemsetAsync(bcnt, 0, NBK * sizeof(int), stream);
    hipMemsetAsync(accum, 0, 2 * sizeof(float), stream);

    k_hist <<<NE / K_A, 256, 0, stream>>>(ei, bcnt);
    k_bscan<<<1, 256, 0, stream>>>(bcnt, bbase, gcnt);
    k_binA <<<NE / K_A, 256, 0, stream>>>(ei, gcnt, edges);
    k_binB <<<NBK, 256, 0, stream>>>(bbase, edges, rowptr, dinv);

    k_cvt  <<<(NN * 8 + 255) / 256, 256, 0, stream>>>((const float4*)emb, dinv, emb16);

    k_l1<<<(NN + 63) / 64, 512, 0, stream>>>(emb16, dinv, rowptr, edges,
                                             (const float4*)W1, b1, h16);
    k_l2<<<NN / 32, 512, 0, stream>>>((const uint4*)h16, dinv, rowptr, edges,
                                      (const float4*)Wmu, bmu, (const float4*)Wls, bls,
                                      out, z16);

    k_loss<<<(2 * NP * 16) / (256 * 4), 256, 0, stream>>>(pos, neg, z16, accum);
    k_fin<<<1, 1, 0, stream>>>(accum, out);
}

// Round 14
// 279.078 us; speedup vs baseline: 1.0305x; 1.0305x over previous
//
#include <hip/hip_runtime.h>
#include <hip/hip_bf16.h>
#include <hip/hip_fp16.h>

#define NN 100000      // nodes
#define NE 1600000     // edges
#define NP 100000      // pos/neg label edges
// EMB=64, HID=128, OUT=64

// ---------------- fp16 helpers ----------------
typedef _Float16 h2v __attribute__((ext_vector_type(2)));

__device__ __forceinline__ float fdot2u(uint a, uint b, float c) {
    union { uint u; h2v h; } ua, ub;
    ua.u = a; ub.u = b;
    return __builtin_amdgcn_fdot2(ua.h, ub.h, c, false);
}

__device__ __forceinline__ uint packh2(float lo, float hi) {
    __half2 h = __floats2half2_rn(lo, hi);
    return *(uint*)&h;
}

__device__ __forceinline__ void h8_to_f(const uint4 u, float* f) {
    const __half2* hp = (const __half2*)&u;
    float2 t0 = __half22float2(hp[0]), t1 = __half22float2(hp[1]);
    float2 t2 = __half22float2(hp[2]), t3 = __half22float2(hp[3]);
    f[0] = t0.x; f[1] = t0.y; f[2] = t1.x; f[3] = t1.y;
    f[4] = t2.x; f[5] = t2.y; f[6] = t3.x; f[7] = t3.y;
}

__device__ __forceinline__ void add8(const uint4 u, float* acc) {
    float f[8]; h8_to_f(u, f);
#pragma unroll
    for (int i = 0; i < 8; ++i) acc[i] += f[i];
}

// ---------------- CSR build: bucket histogram -> scan -> 2-pass counting sort --------
#define RNG 400
#define NBK 250       // NN / RNG
#define K_A 8000      // edges per pass-A block; 200 blocks
#define CAPB 12288    // pass-B LDS staging (mean region 6400)

__global__ __launch_bounds__(256) void k_hist(const int* __restrict__ ei,
                                              int* __restrict__ bcnt) {
    __shared__ int hist[NBK];
    int tid = threadIdx.x;
    int e0 = blockIdx.x * K_A;
    for (int i = tid; i < NBK; i += 256) hist[i] = 0;
    __syncthreads();
    for (int i = tid; i < K_A; i += 256) atomicAdd(&hist[ei[NE + e0 + i] / RNG], 1);
    __syncthreads();
    for (int i = tid; i < NBK; i += 256) if (hist[i]) atomicAdd(&bcnt[i], hist[i]);
}

__global__ __launch_bounds__(256) void k_bscan(const int* __restrict__ bcnt,
                                               int* __restrict__ bbase,
                                               int* __restrict__ gcnt) {
    __shared__ int c[NBK];
    int tid = threadIdx.x;
    if (tid < NBK) c[tid] = bcnt[tid];
    __syncthreads();
    if (tid < 64) {
        int run = 0;
        for (int g = 0; g < NBK; g += 64) {
            int idx = g + tid;
            int v = (idx < NBK) ? c[idx] : 0;
            int inc = v;
#pragma unroll
            for (int off = 1; off < 64; off <<= 1) {
                int t2 = __shfl_up(inc, off);
                if (tid >= off) inc += t2;
            }
            if (idx < NBK) { int ex = run + inc - v; bbase[idx] = ex; gcnt[idx] = ex; }
            run += __shfl(inc, 63);
        }
        if (tid == 0) bbase[NBK] = run;
    }
}

// Pass A: chunk -> bucket-sorted in LDS -> coalesced segment append per bucket.
// Record (4B): src | (dst_local << 17)
__global__ __launch_bounds__(256) void k_binA(const int* __restrict__ ei,
                                              int* __restrict__ gcnt,
                                              int* __restrict__ edges) {
    __shared__ int buf[K_A];                        // 32 KB
    __shared__ int hist[NBK], lofs[NBK + 1], lcnt[NBK], gbase[NBK];
    int tid = threadIdx.x;
    int e0 = blockIdx.x * K_A;
    for (int i = tid; i < NBK; i += 256) { hist[i] = 0; lcnt[i] = 0; }
    __syncthreads();
    for (int i = tid; i < K_A; i += 256) atomicAdd(&hist[ei[NE + e0 + i] / RNG], 1);
    __syncthreads();
    if (tid < 64) {
        int run = 0;
        for (int g = 0; g < NBK; g += 64) {
            int idx = g + tid;
            int v = (idx < NBK) ? hist[idx] : 0;
            int inc = v;
#pragma unroll
            for (int off = 1; off < 64; off <<= 1) {
                int t2 = __shfl_up(inc, off);
                if (tid >= off) inc += t2;
            }
            if (idx < NBK) lofs[idx] = run + inc - v;
            run += __shfl(inc, 63);
        }
        if (tid == 0) lofs[NBK] = run;              // == K_A
    }
    for (int i = tid; i < NBK; i += 256) gbase[i] = atomicAdd(&gcnt[i], hist[i]);
    __syncthreads();
    for (int i = tid; i < K_A; i += 256) {
        int s = ei[e0 + i], d = ei[NE + e0 + i];
        int b = d / RNG;
        int dl = d - b * RNG;
        int p = lofs[b] + atomicAdd(&lcnt[b], 1);
        buf[p] = s | (dl << 17);
    }
    __syncthreads();
    for (int j = tid; j < K_A; j += 256) {
        int loB = 0, hiB = NBK;
        while (hiB - loB > 1) {
            int mid = (loB + hiB) >> 1;
            if (lofs[mid] <= j) loB = mid; else hiB = mid;
        }
        edges[gbase[loB] + (j - lofs[loB])] = buf[j];
    }
}

// Pass B: per bucket -- per-dst histogram -> dinv + rowptr, then in-place CSR reorder.
__global__ __launch_bounds__(256) void k_binB(const int* __restrict__ bbase,
                                              int* __restrict__ edges,
                                              int* __restrict__ rowptr,
                                              float* __restrict__ dinv) {
    __shared__ int buf[CAPB];                       // 48 KB
    __shared__ int hist[RNG], lrp[RNG], lcnt[RNG];
    int tid = threadIdx.x;
    int b = blockIdx.x;
    int lo = b * RNG;
    int base = bbase[b], n = bbase[b + 1] - base;
    for (int i = tid; i < RNG; i += 256) { hist[i] = 0; lcnt[i] = 0; }
    __syncthreads();
    for (int i = tid; i < n; i += 256)
        atomicAdd(&hist[((unsigned)edges[base + i]) >> 17], 1);
    __syncthreads();
    if (tid < 64) {
        int run = 0;
        for (int g = 0; g < RNG; g += 64) {
            int idx = g + tid;
            int v = (idx < RNG) ? hist[idx] : 0;
            int inc = v;
#pragma unroll
            for (int off = 1; off < 64; off <<= 1) {
                int t2 = __shfl_up(inc, off);
                if (tid >= off) inc += t2;
            }
            if (idx < RNG) lrp[idx] = run + inc - v;
            run += __shfl(inc, 63);
        }
    }
    __syncthreads();
    for (int i = tid; i < RNG; i += 256) {
        dinv[lo + i] = rsqrtf((float)hist[i] + 1.0f);
        rowptr[lo + i] = base + lrp[i];
    }
    if (b == NBK - 1 && tid == 0) rowptr[NN] = base + n;
    int ovS0 = -1, ovS1 = -1, ovR0 = 0, ovR1 = 0;
    for (int i = tid; i < n; i += 256) {
        int rec = edges[base + i];
        int dl = ((unsigned)rec) >> 17;
        int src = rec & 0x1FFFF;
        int slot = lrp[dl] + atomicAdd(&lcnt[dl], 1);
        if (slot < CAPB) buf[slot] = src;
        else if (ovS0 < 0) { ovS0 = slot; ovR0 = src; }
        else { ovS1 = slot; ovR1 = src; }
    }
    __syncthreads();
    int lim = n < CAPB ? n : CAPB;
    for (int i = tid; i < lim; i += 256) edges[base + i] = buf[i];
    if (ovS0 >= 0) edges[base + ovS0] = ovR0;
    if (ovS1 >= 0) edges[base + ovS1] = ovR1;
}

// ---------------- emb -> fp16 table, pre-scaled by dinv ----------------
__global__ void k_cvt(const float4* __restrict__ in4, const float* __restrict__ dinv,
                      uint4* __restrict__ out) {
    int t = blockIdx.x * blockDim.x + threadIdx.x;   // NN*8 threads, 8 floats each
    if (t >= NN * 8) return;
    float dv = dinv[t >> 3];
    float4 a = in4[t * 2], b = in4[t * 2 + 1];
    union { __half2 h[4]; uint4 u; } pk;
    pk.h[0] = __floats2half2_rn(a.x * dv, a.y * dv);
    pk.h[1] = __floats2half2_rn(a.z * dv, a.w * dv);
    pk.h[2] = __floats2half2_rn(b.x * dv, b.y * dv);
    pk.h[3] = __floats2half2_rn(b.z * dv, b.w * dv);
    out[t] = pk.u;
}

// ---------------- fused layer 1, WAVE-LOCAL: gather -> relu(agg@W1+b1)*dinv ----------
// 512 threads = 8 waves; each wave owns 8 rows (8 lanes/row gather).
// Only barrier: after weight staging. LDS 24 KB.
__global__ __launch_bounds__(512) void k_l1(const uint4* __restrict__ x16,
                                            const float* __restrict__ dinv,
                                            const int* __restrict__ rowptr,
                                            const int* __restrict__ edges,
                                            const float4* __restrict__ W1_4, // [64][32] f4
                                            const float* __restrict__ b1,
                                            uint2* __restrict__ h16) {
    __shared__ uint4 w16h[32 * 32];    // 16 KB: [kpair][jg] half2 pairs
    __shared__ uint rows16[64 * 32];   // 8 KB: [row][kpair]
    int t = threadIdx.x;
    int base = blockIdx.x * 64;
#pragma unroll
    for (int i = 0; i < 2; ++i) {      // 1024 entries
        int idx = t + i * 512;
        int kp = idx >> 5, jg = idx & 31;
        float4 we = W1_4[(2 * kp) * 32 + jg];
        float4 wo = W1_4[(2 * kp + 1) * 32 + jg];
        w16h[idx] = make_uint4(packh2(we.x, wo.x), packh2(we.y, wo.y),
                               packh2(we.z, wo.z), packh2(we.w, wo.w));
    }
    __syncthreads();                   // weights ready; no further block syncs
    int w = t >> 6;                    // wave id
    // ---- gather phase (wave-local rows w*8 .. w*8+7) ----
    {
        int rl = (t >> 3) & 7, q = t & 7;
        int lrow = w * 8 + rl;
        int r = base + lrow;
        if (r < NN) {
            float acc[8];
            h8_to_f(x16[(size_t)r * 8 + q], acc);    // self term x'[r]
            int j = rowptr[r], j1 = rowptr[r + 1];
            for (; j + 8 <= j1; j += 8) {
                int e[8]; uint4 v[8];
#pragma unroll
                for (int i = 0; i < 8; ++i) e[i] = edges[j + i];
#pragma unroll
                for (int i = 0; i < 8; ++i) v[i] = x16[(size_t)e[i] * 8 + q];
#pragma unroll
                for (int i = 0; i < 8; ++i) add8(v[i], acc);
            }
            if (j + 4 <= j1) {
                int e[4]; uint4 v[4];
#pragma unroll
                for (int i = 0; i < 4; ++i) e[i] = edges[j + i];
#pragma unroll
                for (int i = 0; i < 4; ++i) v[i] = x16[(size_t)e[i] * 8 + q];
#pragma unroll
                for (int i = 0; i < 4; ++i) add8(v[i], acc);
                j += 4;
            }
            for (; j < j1; ++j) add8(x16[(size_t)edges[j] * 8 + q], acc);
            float dr = dinv[r];
#pragma unroll
            for (int i = 0; i < 8; ++i) acc[i] *= dr;
#pragma unroll
            for (int i = 0; i < 4; ++i)
                rows16[lrow * 32 + 4 * q + i] = packh2(acc[2 * i], acc[2 * i + 1]);
        }
    }
    __builtin_amdgcn_wave_barrier();   // wave-local fence (lgkmcnt auto-inserted)
    // ---- matmul phase: wave computes its own 8 rows ----
    int lane = t & 63;
    int jg = lane & 31, rsel = lane >> 5;
    int r0 = w * 8 + rsel * 4;         // 4 rows per lane
    float4 bias = ((const float4*)b1)[jg];
    float acc[4][4];
#pragma unroll
    for (int r2 = 0; r2 < 4; ++r2) {
        acc[r2][0] = bias.x; acc[r2][1] = bias.y; acc[r2][2] = bias.z; acc[r2][3] = bias.w;
    }
#pragma unroll 4
    for (int kp = 0; kp < 32; ++kp) {
        uint f0 = rows16[(r0 + 0) * 32 + kp];
        uint f1 = rows16[(r0 + 1) * 32 + kp];
        uint f2 = rows16[(r0 + 2) * 32 + kp];
        uint f3 = rows16[(r0 + 3) * 32 + kp];
        uint4 wv = w16h[kp * 32 + jg];
        acc[0][0] = fdot2u(f0, wv.x, acc[0][0]); acc[0][1] = fdot2u(f0, wv.y, acc[0][1]);
        acc[0][2] = fdot2u(f0, wv.z, acc[0][2]); acc[0][3] = fdot2u(f0, wv.w, acc[0][3]);
        acc[1][0] = fdot2u(f1, wv.x, acc[1][0]); acc[1][1] = fdot2u(f1, wv.y, acc[1][1]);
        acc[1][2] = fdot2u(f1, wv.z, acc[1][2]); acc[1][3] = fdot2u(f1, wv.w, acc[1][3]);
        acc[2][0] = fdot2u(f2, wv.x, acc[2][0]); acc[2][1] = fdot2u(f2, wv.y, acc[2][1]);
        acc[2][2] = fdot2u(f2, wv.z, acc[2][2]); acc[2][3] = fdot2u(f2, wv.w, acc[2][3]);
        acc[3][0] = fdot2u(f3, wv.x, acc[3][0]); acc[3][1] = fdot2u(f3, wv.y, acc[3][1]);
        acc[3][2] = fdot2u(f3, wv.z, acc[3][2]); acc[3][3] = fdot2u(f3, wv.w, acc[3][3]);
    }
#pragma unroll
    for (int r2 = 0; r2 < 4; ++r2) {
        int row = base + r0 + r2;
        if (row < NN) {
            float dv = dinv[row];
            union { __half2 h[2]; uint2 u; } pk;
            pk.h[0] = __floats2half2_rn(fmaxf(acc[r2][0], 0.0f) * dv,
                                        fmaxf(acc[r2][1], 0.0f) * dv);
            pk.h[1] = __floats2half2_rn(fmaxf(acc[r2][2], 0.0f) * dv,
                                        fmaxf(acc[r2][3], 0.0f) * dv);
            h16[(size_t)row * 32 + jg] = pk.u;
        }
    }
}

// ---------------- fused layer 2, WAVE-LOCAL: gather -> mu/logstd + z16 ----------
// 512 threads = 8 waves; each wave owns 4 rows (16 lanes/row gather, aggH shape).
// Only barrier: after weight staging. LDS 40 KB.
__global__ __launch_bounds__(512) void k_l2(const uint4* __restrict__ x16,
                                            const float* __restrict__ dinv,
                                            const int* __restrict__ rowptr,
                                            const int* __restrict__ edges,
                                            const float4* __restrict__ Wmu4, // [128][16] f4
                                            const float* __restrict__ bmu,
                                            const float4* __restrict__ Wls4, // [128][16] f4
                                            const float* __restrict__ bls,
                                            float* __restrict__ out,
                                            uint2* __restrict__ z16) {
    __shared__ uint4 w16h[64 * 32];    // 32 KB: full [Wmu|Wls] as [kpair][jg]
    __shared__ uint rows16[32 * 64];   // 8 KB: [row][kpair]
    int t = threadIdx.x;
    int base = blockIdx.x * 32;        // NN % 32 == 0, no tail
#pragma unroll
    for (int i = 0; i < 4; ++i) {      // 2048 entries
        int idx = t + i * 512;
        int kp = idx >> 5, jg = idx & 31;
        int jj = (jg < 16) ? jg : (jg - 16);
        const float4* W = (jg < 16) ? Wmu4 : Wls4;
        float4 we = W[(2 * kp) * 16 + jj];
        float4 wo = W[(2 * kp + 1) * 16 + jj];
        w16h[idx] = make_uint4(packh2(we.x, wo.x), packh2(we.y, wo.y),
                               packh2(we.z, wo.z), packh2(we.w, wo.w));
    }
    __syncthreads();                   // weights ready; no further block syncs
    int w = t >> 6;                    // wave id
    // ---- gather phase (wave-local rows w*4 .. w*4+3): 16 lanes/row x uint4 ----
    {
        int rl = (t >> 4) & 3, q = t & 15;
        int lrow = w * 4 + rl;
        int r = base + lrow;
        float acc[8];
        h8_to_f(x16[(size_t)r * 16 + q], acc);       // self term h'[r]
        int j = rowptr[r], j1 = rowptr[r + 1];
        for (; j + 8 <= j1; j += 8) {
            int e[8]; uint4 v[8];
#pragma unroll
            for (int i = 0; i < 8; ++i) e[i] = edges[j + i];
#pragma unroll
            for (int i = 0; i < 8; ++i) v[i] = x16[(size_t)e[i] * 16 + q];
#pragma unroll
            for (int i = 0; i < 8; ++i) add8(v[i], acc);
        }
        if (j + 4 <= j1) {
            int e[4]; uint4 v[4];
#pragma unroll
            for (int i = 0; i < 4; ++i) e[i] = edges[j + i];
#pragma unroll
            for (int i = 0; i < 4; ++i) v[i] = x16[(size_t)e[i] * 16 + q];
#pragma unroll
            for (int i = 0; i < 4; ++i) add8(v[i], acc);
            j += 4;
        }
        for (; j < j1; ++j) add8(x16[(size_t)edges[j] * 16 + q], acc);
        float dr = dinv[r];
#pragma unroll
        for (int i = 0; i < 8; ++i) acc[i] *= dr;
#pragma unroll
        for (int i = 0; i < 4; ++i)
            rows16[lrow * 64 + 4 * q + i] = packh2(acc[2 * i], acc[2 * i + 1]);
    }
    __builtin_amdgcn_wave_barrier();   // wave-local fence (lgkmcnt auto-inserted)
    // ---- matmul phase: wave computes its own 4 rows (2 per lane) ----
    int lane = t & 63;
    int jg = lane & 31, rsel = lane >> 5;
    int r0 = w * 4 + rsel * 2;
    float4 bias = (jg < 16) ? ((const float4*)bmu)[jg] : ((const float4*)bls)[jg - 16];
    float acc[2][4];
#pragma unroll
    for (int r2 = 0; r2 < 2; ++r2) {
        acc[r2][0] = bias.x; acc[r2][1] = bias.y; acc[r2][2] = bias.z; acc[r2][3] = bias.w;
    }
#pragma unroll 8
    for (int kp = 0; kp < 64; ++kp) {
        uint f0 = rows16[(r0 + 0) * 64 + kp];
        uint f1 = rows16[(r0 + 1) * 64 + kp];
        uint4 wv = w16h[kp * 32 + jg];
        acc[0][0] = fdot2u(f0, wv.x, acc[0][0]); acc[0][1] = fdot2u(f0, wv.y, acc[0][1]);
        acc[0][2] = fdot2u(f0, wv.z, acc[0][2]); acc[0][3] = fdot2u(f0, wv.w, acc[0][3]);
        acc[1][0] = fdot2u(f1, wv.x, acc[1][0]); acc[1][1] = fdot2u(f1, wv.y, acc[1][1]);
        acc[1][2] = fdot2u(f1, wv.z, acc[1][2]); acc[1][3] = fdot2u(f1, wv.w, acc[1][3]);
    }
    float4* out4 = (float4*)out;
    if (jg < 16) {
#pragma unroll
        for (int r2 = 0; r2 < 2; ++r2) {
            int row = base + r0 + r2;
            out4[(size_t)row * 16 + jg] =
                make_float4(acc[r2][0], acc[r2][1], acc[r2][2], acc[r2][3]);
            union { __half2 h[2]; uint2 u; } pk;
            pk.h[0] = __floats2half2_rn(acc[r2][0], acc[r2][1]);
            pk.h[1] = __floats2half2_rn(acc[r2][2], acc[r2][3]);
            z16[(size_t)row * 16 + jg] = pk.u;
        }
    } else {
#pragma unroll
        for (int r2 = 0; r2 < 2; ++r2) {
            int row = base + r0 + r2;
            float4 o = make_float4(fminf(acc[r2][0], 10.0f), fminf(acc[r2][1], 10.0f),
                                   fminf(acc[r2][2], 10.0f), fminf(acc[r2][3], 10.0f));
            out4[(size_t)NN * 16 + (size_t)row * 16 + (jg - 16)] = o;
        }
    }
}

// ---------------- decoder loss: fp16 z, 4 edges per 16-lane group, fdot2 ----------------
__global__ __launch_bounds__(256) void k_loss(const int* __restrict__ pos,
                                              const int* __restrict__ neg,
                                              const uint2* __restrict__ z16,
                                              float* __restrict__ accum) {
    int t = blockIdx.x * blockDim.x + threadIdx.x;
    int grp = t >> 4, q = t & 15;
    int e0 = grp * 4;                          // 4 consecutive ids in [0, 2*NP)
    bool isNeg = e0 >= NP;                     // uniform within group (NP % 4 == 0)
    const int* idx = isNeg ? neg : pos;
    int eb = isNeg ? e0 - NP : e0;
    int a0 = idx[eb + 0], b0 = idx[NP + eb + 0];
    int a1 = idx[eb + 1], b1 = idx[NP + eb + 1];
    int a2 = idx[eb + 2], b2 = idx[NP + eb + 2];
    int a3 = idx[eb + 3], b3 = idx[NP + eb + 3];
    uint2 ua0 = z16[(size_t)a0 * 16 + q], ub0 = z16[(size_t)b0 * 16 + q];
    uint2 ua1 = z16[(size_t)a1 * 16 + q], ub1 = z16[(size_t)b1 * 16 + q];
    uint2 ua2 = z16[(size_t)a2 * 16 + q], ub2 = z16[(size_t)b2 * 16 + q];
    uint2 ua3 = z16[(size_t)a3 * 16 + q], ub3 = z16[(size_t)b3 * 16 + q];
    float d0 = fdot2u(ua0.y, ub0.y, fdot2u(ua0.x, ub0.x, 0.0f));
    float d1 = fdot2u(ua1.y, ub1.y, fdot2u(ua1.x, ub1.x, 0.0f));
    float d2 = fdot2u(ua2.y, ub2.y, fdot2u(ua2.x, ub2.x, 0.0f));
    float d3 = fdot2u(ua3.y, ub3.y, fdot2u(ua3.x, ub3.x, 0.0f));
#pragma unroll
    for (int off = 1; off < 16; off <<= 1) {
        d0 += __shfl_xor(d0, off);
        d1 += __shfl_xor(d1, off);
        d2 += __shfl_xor(d2, off);
        d3 += __shfl_xor(d3, off);
    }
    __shared__ float bsum[2];
    if (threadIdx.x < 2) bsum[threadIdx.x] = 0.0f;
    __syncthreads();
    if (q == 0) {
        float term;
        if (isNeg) {
            term = logf(1.0f - 1.0f / (1.0f + expf(-d0)) + 1e-15f)
                 + logf(1.0f - 1.0f / (1.0f + expf(-d1)) + 1e-15f)
                 + logf(1.0f - 1.0f / (1.0f + expf(-d2)) + 1e-15f)
                 + logf(1.0f - 1.0f / (1.0f + expf(-d3)) + 1e-15f);
        } else {
            term = logf(1.0f / (1.0f + expf(-d0)) + 1e-15f)
                 + logf(1.0f / (1.0f + expf(-d1)) + 1e-15f)
                 + logf(1.0f / (1.0f + expf(-d2)) + 1e-15f)
                 + logf(1.0f / (1.0f + expf(-d3)) + 1e-15f);
        }
        atomicAdd(&bsum[isNeg ? 1 : 0], term);
    }
    __syncthreads();
    if (threadIdx.x < 2) atomicAdd(&accum[threadIdx.x], bsum[threadIdx.x]);
}

__global__ void k_fin(const float* __restrict__ accum, float* __restrict__ out) {
    out[(size_t)NN * 128] = -(accum[0] + accum[1]) * (1.0f / (float)NP);
}

extern "C" void kernel_launch(void* const* d_in, const int* in_sizes, int n_in,
                              void* d_out, int out_size, void* d_ws, size_t ws_size,
                              hipStream_t stream) {
    const float* emb = (const float*)d_in[0];
    const int*   ei  = (const int*)d_in[1];
    const float* W1  = (const float*)d_in[2];
    const float* b1  = (const float*)d_in[3];
    const float* Wmu = (const float*)d_in[4];
    const float* bmu = (const float*)d_in[5];
    const float* Wls = (const float*)d_in[6];
    const float* bls = (const float*)d_in[7];
    const int*   pos = (const int*)d_in[8];
    const int*   neg = (const int*)d_in[9];
    float* out = (float*)d_out;

    char* ws = (char*)d_ws;
    // small buffers
    float* dinv   = (float*)(ws);                        // 400 KB  (written by k_binB)
    int*   rowptr = (int*)  (ws + (512 << 10));          // 400 KB + 4 (written by k_binB)
    int*   bcnt   = (int*)  (ws + (1024 << 10));         // 1 KB
    int*   bbase  = (int*)  (ws + (1028 << 10));         // 1 KB + 4
    int*   gcnt   = (int*)  (ws + (1032 << 10));         // 1 KB
    float* accum  = (float*)(ws + (1040 << 10));         // 8 B
    // big buffers. Liveness:
    //   edges  [k_binA .. k_l2]                            6.4 MB (4B records)
    //   h16    [k_l1 .. k_l2]                              25.6 MB
    //   emb16  [k_cvt .. k_l1]                             12.8 MB
    //   z16    [k_l2 .. k_loss]   ALIASES emb16 (dead)     12.8 MB
    const size_t OFF_EDGES = (2048 << 10);                       // +6.4 MB
    const size_t OFF_H16   = OFF_EDGES + (size_t)NE * 4;         // +25.6 MB
    const size_t OFF_E16   = OFF_H16 + (size_t)NN * 128 * 2;     // +12.8 MB
    int*   edges  = (int*)(ws + OFF_EDGES);
    uint2* h16    = (uint2*)(ws + OFF_H16);
    uint4* emb16  = (uint4*)(ws + OFF_E16);
    uint2* z16    = (uint2*)(ws + OFF_E16);              // emb16 dead by k_l2

    hipMemsetAsync(bcnt, 0, NBK * sizeof(int), stream);
    hipMemsetAsync(accum, 0, 2 * sizeof(float), stream);

    k_hist <<<NE / K_A, 256, 0, stream>>>(ei, bcnt);
    k_bscan<<<1, 256, 0, stream>>>(bcnt, bbase, gcnt);
    k_binA <<<NE / K_A, 256, 0, stream>>>(ei, gcnt, edges);
    k_binB <<<NBK, 256, 0, stream>>>(bbase, edges, rowptr, dinv);

    k_cvt  <<<(NN * 8 + 255) / 256, 256, 0, stream>>>((const float4*)emb, dinv, emb16);

    k_l1<<<(NN + 63) / 64, 512, 0, stream>>>(emb16, dinv, rowptr, edges,
                                             (const float4*)W1, b1, h16);
    k_l2<<<NN / 32, 512, 0, stream>>>((const uint4*)h16, dinv, rowptr, edges,
                                      (const float4*)Wmu, bmu, (const float4*)Wls, bls,
                                      out, z16);

    k_loss<<<(2 * NP * 16) / (256 * 4), 256, 0, stream>>>(pos, neg, z16, accum);
    k_fin<<<1, 1, 0, stream>>>(accum, out);
}